// Round 1
// 165.343 us; speedup vs baseline: 1.2138x; 1.2138x over previous
//
#include <hip/hip_runtime.h>
#include <hip/hip_bf16.h>
#include <math.h>

#define N_NODES 50000
#define N_EDGES 800000
#define CAP 32          // bucket row = 32 ushorts = exactly one 64B line
#define MAX_OVF 8192    // overflow list; P(deg>32)~1e-4 -> ~5 nodes, ~50 edges

// Two-phase binning (replaces global-atomic scatter):
#define NBIN 196                    // ceil(N_NODES/256) coarse bins of 256 nodes
#define KA_BLOCKS 256               // binning blocks
#define EPB (N_EDGES / KA_BLOCKS)   // 3125 edges per block (exact)
#define SUBCAP 48                   // per-(bin,block) arena cap: mean 16, sigma 4 -> 8 sigma

#define UV_BLOCKS 1024
#define W2_BLOCKS 16
#define P1_GRID (KA_BLOCKS + UV_BLOCKS + W2_BLOCKS)

typedef __bf16 bf16x8 __attribute__((ext_vector_type(8)));
typedef float f32x4 __attribute__((ext_vector_type(4)));

// ---------------------------------------------------------------------------
// Phase 1 (fused, all independent work):
//   blocks [0,256):            edge binning -> per-(bin,block) arena chunks.
//                              LDS histogram+rank; ZERO global atomics in the
//                              common path (vs 800k device-scope atomicAdds,
//                              which write through ~60B/op = the old 48MB
//                              WRITE_SIZE @ ~930GB/s atomic-path ceiling).
//   blocks [256,1280):         U[i]=(W1a-W1b)x_i+b1 ; V[j]=W1b x_j (wave/node)
//   blocks [1280,1296):        W2 -> bf16
// cur[] poison-base trick (same as old ucounts): cur[0] untouched = base;
// cur[16] = ovf cursor; cur[32] = arena-overflow force-scan flag.
// ---------------------------------------------------------------------------
__global__ __launch_bounds__(256) void phase1_kernel(
    const float* __restrict__ x, const float* __restrict__ W1,
    const float* __restrict__ b1, const float* __restrict__ W2,
    const int* __restrict__ ei,
    float* __restrict__ U, float* __restrict__ V, __bf16* __restrict__ w2h,
    unsigned* __restrict__ arena, unsigned* __restrict__ cntA,
    unsigned* __restrict__ cur, int2* __restrict__ ovf)
{
    __shared__ unsigned sh_hist[256];
    __shared__ unsigned sh_pack[EPB];        // src | dlow<<16 | bin<<24
    __shared__ unsigned short sh_rank[EPB];  // rank within (block,bin)

    const int blk = blockIdx.x;
    const int tid = threadIdx.x;

    if (blk < KA_BLOCKS) {
        // ---- edge binning ----
        sh_hist[tid] = 0;
        __syncthreads();
        const int e0 = blk * EPB;
        for (int i = tid; i < EPB; i += 256) {
            int s = ei[e0 + i];
            int d = ei[N_EDGES + e0 + i];
            unsigned bin = (unsigned)d >> 8;
            unsigned r = atomicAdd(&sh_hist[bin], 1u);
            sh_pack[i] = (unsigned)s | ((unsigned)(d & 255) << 16) | (bin << 24);
            sh_rank[i] = (unsigned short)r;
        }
        __syncthreads();
        if (tid < NBIN) cntA[tid * KA_BLOCKS + blk] = sh_hist[tid];
        const unsigned base = cur[0];
        for (int i = tid; i < EPB; i += 256) {
            unsigned p = sh_pack[i];
            unsigned r = sh_rank[i];
            unsigned bin = p >> 24;
            if (r < SUBCAP) {
                arena[((size_t)bin * KA_BLOCKS + blk) * SUBCAP + r] = p;
            } else {
                // arena overflow (statistically never): exact fallback
                atomicAdd(&cur[32], 1u);  // force node_kernel to scan ovf
                unsigned o = atomicAdd(&cur[16], 1u) - base;
                int d = (int)(bin * 256 + ((p >> 16) & 255u));
                int s = (int)(p & 0xFFFFu);
                if (o < MAX_OVF) ovf[o] = make_int2(d, s);
            }
        }
    } else if (blk < KA_BLOCKS + UV_BLOCKS) {
        // ---- U/V prep ----
        const int lane = tid & 63;
        const int ublk = blk - KA_BLOCKS;
        const int wave = (int)((ublk * 256 + tid) >> 6);
        const int nwav = UV_BLOCKS * 4;

        float wa[64], wb[64];
#pragma unroll
        for (int k4 = 0; k4 < 16; ++k4) {
            float4 pa = *(const float4*)(W1 + lane * 128 + k4 * 4);
            float4 pb = *(const float4*)(W1 + lane * 128 + 64 + k4 * 4);
            wa[k4 * 4 + 0] = pa.x - pb.x;  wb[k4 * 4 + 0] = pb.x;
            wa[k4 * 4 + 1] = pa.y - pb.y;  wb[k4 * 4 + 1] = pb.y;
            wa[k4 * 4 + 2] = pa.z - pb.z;  wb[k4 * 4 + 2] = pb.z;
            wa[k4 * 4 + 3] = pa.w - pb.w;  wb[k4 * 4 + 3] = pb.w;
        }
        const float bias = b1[lane];

        for (int i = wave; i < N_NODES; i += nwav) {
            float xv = x[i * 64 + lane];
            float u = bias, v = 0.f;
#pragma unroll
            for (int k = 0; k < 64; ++k) {
                float xk = __int_as_float(
                    __builtin_amdgcn_readlane(__float_as_int(xv), k));
                u = fmaf(wa[k], xk, u);
                v = fmaf(wb[k], xk, v);
            }
            U[i * 64 + lane] = u;
            V[i * 64 + lane] = v;
        }
    } else {
        const int i = (blk - KA_BLOCKS - UV_BLOCKS) * 256 + tid;
        if (i < 64 * 64) w2h[i] = (__bf16)W2[i];
    }
}

// ---------------------------------------------------------------------------
// Phase 2: one block per coarse bin. Thread t drains arena chunk t (uint4
// batched), tickets each edge with a 256-entry LDS counter (800k LDS atomics
// replace 800k device-scope global atomics), writes the same bucket layout,
// then writes EXACT per-node counts (no poison-base needed for counts).
// Bucket stores land in a 16KB window per block -> L2-coalesced lines.
// ---------------------------------------------------------------------------
__global__ __launch_bounds__(256) void bucket_kernel(
    const unsigned* __restrict__ arena, const unsigned* __restrict__ cntA,
    unsigned* __restrict__ counts, unsigned short* __restrict__ buckets,
    unsigned* __restrict__ cur, int2* __restrict__ ovf)
{
    __shared__ unsigned lcnt[256];
    const int bin = blockIdx.x;
    const int tid = threadIdx.x;
    lcnt[tid] = 0;
    __syncthreads();

    const unsigned base = cur[0];
    unsigned n = cntA[(size_t)bin * KA_BLOCKS + tid];  // chunk 'tid' of this bin
    if (n > SUBCAP) n = SUBCAP;                        // excess went to ovf
    const unsigned* ch = arena + ((size_t)bin * KA_BLOCKS + tid) * SUBCAP;

    for (unsigned j0 = 0; j0 < n; j0 += 4) {
        uint4 q = *(const uint4*)(ch + j0);            // chunk base is 192B-aligned
        unsigned w[4] = {q.x, q.y, q.z, q.w};
        unsigned m = n - j0; if (m > 4) m = 4;
#pragma unroll
        for (unsigned k = 0; k < 4; ++k) {
            if (k >= m) break;
            unsigned p = w[k];
            unsigned dlow = (p >> 16) & 255u;
            unsigned s = p & 0xFFFFu;
            unsigned pos = atomicAdd(&lcnt[dlow], 1u);
            int d = bin * 256 + (int)dlow;
            if (pos < CAP) {
                buckets[(size_t)d * CAP + pos] = (unsigned short)s;
            } else {
                unsigned o = atomicAdd(&cur[16], 1u) - base;
                if (o < MAX_OVF) ovf[o] = make_int2(d, (int)s);
            }
        }
    }
    __syncthreads();
    const int node = bin * 256 + tid;
    if (node < N_NODES) counts[node] = lcnt[tid];
}

// ---------------------------------------------------------------------------
// Tile compute: unchanged (R7 WIN structure).
// ---------------------------------------------------------------------------
__device__ __forceinline__ void tile_mfma_max(
    const float4* __restrict__ uf4, const float4* __restrict__ v4,
    const __bf16* __restrict__ w2h, int m, int q, int lim,
    float* __restrict__ rm)
{
    bf16x8 ahi[2], alo[2];
#pragma unroll
    for (int s = 0; s < 2; ++s) {
        const float4 a = uf4[2 * s], b = uf4[2 * s + 1];
        const float4 c = v4[2 * s],  d = v4[2 * s + 1];
        float hv[8] = {a.x + c.x, a.y + c.y, a.z + c.z, a.w + c.w,
                       b.x + d.x, b.y + d.y, b.z + d.z, b.w + d.w};
#pragma unroll
        for (int j = 0; j < 8; ++j) {
            float h = fmaxf(hv[j], 0.01f * hv[j]);   // LeakyReLU
            __bf16 hb = (__bf16)h;
            ahi[s][j] = hb;
            alo[s][j] = (__bf16)(h - (float)hb);     // residual
        }
    }
#pragma unroll
    for (int t = 0; t < 4; ++t) {
        const bf16x8 b0 = *(const bf16x8*)(w2h + (t * 16 + m) * 64 + q * 8);
        const bf16x8 b1 = *(const bf16x8*)(w2h + (t * 16 + m) * 64 + 32 + q * 8);
        f32x4 acc = {0.f, 0.f, 0.f, 0.f};
        acc = __builtin_amdgcn_mfma_f32_16x16x32_bf16(ahi[0], b0, acc, 0, 0, 0);
        acc = __builtin_amdgcn_mfma_f32_16x16x32_bf16(alo[0], b0, acc, 0, 0, 0);
        acc = __builtin_amdgcn_mfma_f32_16x16x32_bf16(ahi[1], b1, acc, 0, 0, 0);
        acc = __builtin_amdgcn_mfma_f32_16x16x32_bf16(alo[1], b1, acc, 0, 0, 0);
        float v = -INFINITY;
#pragma unroll
        for (int r = 0; r < 4; ++r)
            if (4 * q + r < lim) v = fmaxf(v, acc[r]);   // mask garbage rows
        v = fmaxf(v, __shfl_xor(v, 16, 64));
        v = fmaxf(v, __shfl_xor(v, 32, 64));
        rm[t] = fmaxf(rm[t], v);
    }
}

__device__ __forceinline__ void load_v4(const float* __restrict__ V,
                                        unsigned si, int q, float4* v4)
{
    const float* b0 = V + (size_t)si * 64 + q * 8;
    v4[0] = ((const float4*)b0)[0];
    v4[1] = ((const float4*)b0)[1];
    const float* b1 = b0 + 32;
    v4[2] = ((const float4*)b1)[0];
    v4[3] = ((const float4*)b1)[1];
}

// ---------------------------------------------------------------------------
// K3: wave per node, 2-deep software pipeline (unchanged structure).
// counts[] are now exact plain degrees from bucket_kernel. Bucket values are
// still poison-safe (clamped); validity enforced by the -INF row mask.
// ---------------------------------------------------------------------------
__global__ __launch_bounds__(256, 4) void node_kernel(
    const unsigned* __restrict__ counts, const unsigned short* __restrict__ buckets,
    const int2* __restrict__ ovf,
    const float* __restrict__ U, const float* __restrict__ V,
    const __bf16* __restrict__ w2h, const float* __restrict__ b2,
    float* __restrict__ out, const unsigned* __restrict__ cur)
{
    const int lane = threadIdx.x & 63;
    const int m    = lane & 15;
    const int q    = lane >> 4;
    const int wave = (int)((blockIdx.x * blockDim.x + threadIdx.x) >> 6);
    const int nwav = (int)((gridDim.x * blockDim.x) >> 6);

    const float b2v = b2[lane];
    const unsigned base  = cur[0];
    const unsigned force = cur[32] - base;   // arena-overflow force-scan flag
    const unsigned nou   = cur[16] - base;   // total ovf entries

    // ---- prologue: arm node A fully; arm bkt/cnt for node B ----
    const int nA0 = wave;                        // wave < 4096 < N_NODES
    int pB = nA0 + nwav; if (pB >= N_NODES) pB = N_NODES - 1;

    unsigned cntA = counts[nA0];
    int      bktA = buckets[nA0 * CAP + m];
    float4 ufA[4];
    {
        const float* ub0 = U + (size_t)nA0 * 64 + q * 8;
        ufA[0] = ((const float4*)ub0)[0]; ufA[1] = ((const float4*)ub0)[1];
        ufA[2] = ((const float4*)(ub0 + 32))[0]; ufA[3] = ((const float4*)(ub0 + 32))[1];
    }
    unsigned cntB = counts[pB];
    int      bktB = buckets[pB * CAP + m];

    float4 vA[4];
    {
        unsigned usiA = (unsigned)bktA;
        if (usiA >= N_NODES) usiA = N_NODES - 1;   // poison-safe clamp
        load_v4(V, usiA, q, vA);
    }
    float4 ufB[4];
    {
        const float* ub0 = U + (size_t)pB * 64 + q * 8;
        ufB[0] = ((const float4*)ub0)[0]; ufB[1] = ((const float4*)ub0)[1];
        ufB[2] = ((const float4*)(ub0 + 32))[0]; ufB[3] = ((const float4*)(ub0 + 32))[1];
    }

    for (int n = nA0; n < N_NODES; n += nwav) {
        int pC = n + 2 * nwav; if (pC >= N_NODES) pC = N_NODES - 1;

        // (1) issue V for node B
        unsigned usiB = (unsigned)bktB;
        if (usiB >= N_NODES) usiB = N_NODES - 1;
        float4 vB[4];
        load_v4(V, usiB, q, vB);

        // (2) issue bkt/cnt for node C
        unsigned cntC = counts[pC];
        int      bktC = buckets[pC * CAP + m];

        // (3) compute node A = n
        const unsigned c = cntA;
        const int deg = (c < CAP) ? (int)c : CAP;

        float rm[4] = {-INFINITY, -INFINITY, -INFINITY, -INFINITY};
        const int lim0 = (deg < 16) ? deg : 16;
        tile_mfma_max(ufA, vA, w2h, m, q, lim0, rm);     // tile 0 (pre-armed)

        for (int base16 = 16; base16 < deg; base16 += 16) {  // tile 1 (deg > 16)
            int el = base16 + m; if (el > deg - 1) el = deg - 1;   // dup-pad
            unsigned si = (unsigned)buckets[n * CAP + el];         // valid entry
            float4 v4[4];
            load_v4(V, si, q, v4);
            tile_mfma_max(ufA, v4, w2h, m, q, 16, rm);
        }

        if (c > CAP || force != 0u) {   // exact-correctness fallback
            int no = (nou < MAX_OVF) ? (int)nou : MAX_OVF;
            for (int o = 0; o < no; ++o) {
                const int2 ds = ovf[o];
                if (ds.x != n) continue;
                float4 v4[4];
                load_v4(V, (unsigned)ds.y, q, v4);
                tile_mfma_max(ufA, v4, w2h, m, q, 16, rm);
            }
        }

        const float sel = (q == 0) ? rm[0] : (q == 1) ? rm[1]
                        : (q == 2) ? rm[2] : rm[3];      // col == lane
        out[(size_t)n * 64 + lane] = (c != 0u) ? tanhf(sel + b2v) : 0.f;

        // (4) rotate pipeline state; issue U for next B
        cntA = cntB; cntB = cntC;
        bktB = bktC;
#pragma unroll
        for (int i = 0; i < 4; ++i) { ufA[i] = ufB[i]; vA[i] = vB[i]; }
        {
            const float* ub0 = U + (size_t)pC * 64 + q * 8;   // next iter's B == pC
            ufB[0] = ((const float4*)ub0)[0]; ufB[1] = ((const float4*)ub0)[1];
            ufB[2] = ((const float4*)(ub0 + 32))[0]; ufB[3] = ((const float4*)(ub0 + 32))[1];
        }
    }
}

// ---------------------------------------------------------------------------
extern "C" void kernel_launch(void* const* d_in, const int* in_sizes, int n_in,
                              void* d_out, int out_size, void* d_ws, size_t ws_size,
                              hipStream_t stream)
{
    const float* x  = (const float*)d_in[0];
    const int*   ei = (const int*)d_in[1];
    const float* W1 = (const float*)d_in[2];
    const float* b1 = (const float*)d_in[3];
    const float* W2 = (const float*)d_in[4];
    const float* b2 = (const float*)d_in[5];
    float* out = (float*)d_out;

    char* p = (char*)d_ws;
    float* U = (float*)p;                  p += (size_t)N_NODES * 64 * 4;
    float* V = (float*)p;                  p += (size_t)N_NODES * 64 * 4;
    unsigned* arena = (unsigned*)p;        p += (size_t)NBIN * KA_BLOCKS * SUBCAP * 4;
    unsigned short* buckets = (unsigned short*)p;
                                           p += (size_t)N_NODES * CAP * 2;
    __bf16* w2h = (__bf16*)p;              p += 64 * 64 * 2;
    unsigned* cntA = (unsigned*)p;         p += (size_t)NBIN * KA_BLOCKS * 4;
    unsigned* counts = (unsigned*)p;       p += (size_t)((N_NODES + 63) / 64) * 64 * 4;
    unsigned* cur = (unsigned*)p;          p += 64 * 4;
    int2* ovf = (int2*)p;                  p += (size_t)MAX_OVF * 8;

    phase1_kernel<<<P1_GRID, 256, 0, stream>>>(x, W1, b1, W2, ei,
                                               U, V, w2h, arena, cntA, cur, ovf);
    bucket_kernel<<<NBIN, 256, 0, stream>>>(arena, cntA, counts, buckets, cur, ovf);
    node_kernel<<<1024, 256, 0, stream>>>(counts, buckets, ovf,
                                          U, V, w2h, b2, out, cur);
}